// Round 6
// baseline (892.151 us; speedup 1.0000x reference)
//
#include <hip/hip_runtime.h>

// B=4, S=2048, D=1024, H=16, head_dim=64. Inputs fp32, output fp32.
// MFMA bf16 pipeline; fp32 accumulate. 2-pass split-bf16 for Q/K projections.
// Attention: un-shifted softmax (scores bounded ~50 -> exp fits fp32), per-lane
// partial denominators, single epilogue reduce -> zero in-loop shuffles.
// ws (64MB): Xh[16] | Qb/ctx[16] | Kb[16] | Vt[16]  (Wo^T overlays Xh after its death)
// d_out (32MB) pre-final scratch: Xl[16] | Wqt[2] | Wkt[2] | Wvt[2] | mask_f32[32KB]

#define Bb 4
#define Ss 2048
#define Dd 1024
#define Hh 16
#define SZt 8388608

typedef short bf16x8 __attribute__((ext_vector_type(8)));
typedef float f32x4 __attribute__((ext_vector_type(4)));
typedef unsigned short u16;

__device__ __forceinline__ float bf2f(u16 u) {
    return __builtin_bit_cast(float, ((unsigned)u) << 16);
}
__device__ __forceinline__ u16 f2bf(float f) {
    unsigned u = __builtin_bit_cast(unsigned, f);
    unsigned r = 0x7FFFu + ((u >> 16) & 1u);
    return (u16)((u + r) >> 16);
}
__device__ __forceinline__ bf16x8 ldfrag(const u16* p) {
    return __builtin_bit_cast(bf16x8, *(const uint4*)p);
}
__device__ __forceinline__ f32x4 mfma16(bf16x8 a, bf16x8 b, f32x4 c) {
    return __builtin_amdgcn_mfma_f32_16x16x32_bf16(a, b, c, 0, 0, 0);
}

// ---------------- mask normalization (dtype auto-detect; verified) -> float 0/1 ----------------
__global__ void normalize_mask(const unsigned char* __restrict__ raw, float* __restrict__ out, int n) {
    __shared__ int flags;
    if (threadIdx.x == 0) flags = 0;
    __syncthreads();
    int f = 0;
    for (int i = threadIdx.x; i < n; i += blockDim.x) {
        unsigned char c = raw[i];
        if ((i & 3) != 0 && c) f |= 1;
        if ((i & 3) == 1 && c >= 2) f |= 2;
        if ((i & 3) == 3 && c >= 2) f |= 4;
    }
    if (f) atomicOr(&flags, f);
    __syncthreads();
    int fl = flags;
    int layout;                 // 0=int32, 1=u8, 2=bf16, 3=f32
    if (!(fl & 1)) layout = 0;
    else if (fl & 2) layout = 2;
    else if (fl & 4) layout = 3;
    else layout = 1;
    for (int i = threadIdx.x; i < n; i += blockDim.x) {
        int v;
        if (layout == 0)      v = ((const int*)raw)[i];
        else if (layout == 1) v = raw[i];
        else if (layout == 2) v = ((const u16*)raw)[i] != 0;
        else                  v = ((const unsigned*)raw)[i] != 0;
        out[i] = (v != 0) ? 1.0f : 0.0f;
    }
}

// ---------------- X fp32 -> hi/lo bf16 split ----------------
__global__ __launch_bounds__(256) void convert_x(const float* __restrict__ X,
                                                 u16* __restrict__ Xh, u16* __restrict__ Xl) {
    size_t i = ((size_t)blockIdx.x * 256 + threadIdx.x) * 4;
    float4 v = *(const float4*)(X + i);
    u16 h0 = f2bf(v.x), h1 = f2bf(v.y), h2 = f2bf(v.z), h3 = f2bf(v.w);
    u16 l0 = f2bf(v.x - bf2f(h0)), l1 = f2bf(v.y - bf2f(h1));
    u16 l2 = f2bf(v.z - bf2f(h2)), l3 = f2bf(v.w - bf2f(h3));
    uint2 ph = { (unsigned)h0 | ((unsigned)h1 << 16), (unsigned)h2 | ((unsigned)h3 << 16) };
    uint2 pl = { (unsigned)l0 | ((unsigned)l1 << 16), (unsigned)l2 | ((unsigned)l3 << 16) };
    *(uint2*)(Xh + i) = ph;
    *(uint2*)(Xl + i) = pl;
}

// ---------------- W [K][N] fp32 -> Wt [N][K] bf16 (tiled transpose) ----------------
__global__ __launch_bounds__(256) void transpose_w(const float* __restrict__ W, u16* __restrict__ Wt) {
    __shared__ float t[32][33];
    const int tx = threadIdx.x, ty = threadIdx.y;
    const int n0 = blockIdx.x * 32, k0 = blockIdx.y * 32;
    #pragma unroll
    for (int i = 0; i < 4; i++)
        t[ty + i * 8][tx] = W[(size_t)(k0 + ty + i * 8) * Dd + n0 + tx];
    __syncthreads();
    #pragma unroll
    for (int i = 0; i < 4; i++)
        Wt[(size_t)(n0 + ty + i * 8) * Dd + k0 + tx] = f2bf(t[tx][ty + i * 8]);
}

// ---------------- MFMA GEMM, no LDS: C[8192,1024] = A[8192,1024] @ Wt^T + bias ----------------
// PASSES: 1 = Ah only; 2 = Ah + Al (split-fp32 precision).
// OUTMODE: 0 = bf16 [M][N]; 1 = bf16 V-transposed [b][h][d][s]; 2 = fp32 [M][N].
template <int PASSES, int OUTMODE>
__global__ __launch_bounds__(256) void gemm_mfma(
    const u16* __restrict__ Ah, const u16* __restrict__ Al,
    const u16* __restrict__ Wt, const float* __restrict__ bias,
    void* __restrict__ Cout)
{
    const int tid = threadIdx.x, lane = tid & 63, wave = tid >> 6;
    const int wm = wave >> 1, wn = wave & 1;
    const int bm = blockIdx.y * 128, bn = blockIdx.x * 128;
    const int l15 = lane & 15, lq = lane >> 4;
    f32x4 acc[4][4] = {};
    const u16 *ap[4], *alp[4], *bp[4];
    #pragma unroll
    for (int mt = 0; mt < 4; mt++) {
        size_t row = bm + wm * 64 + mt * 16 + l15;
        ap[mt] = Ah + row * Dd + lq * 8;
        if (PASSES == 2) alp[mt] = Al + row * Dd + lq * 8;
    }
    #pragma unroll
    for (int nt = 0; nt < 4; nt++) {
        size_t col = bn + wn * 64 + nt * 16 + l15;
        bp[nt] = Wt + col * Dd + lq * 8;
    }
    #pragma unroll 2
    for (int k = 0; k < Dd; k += 32) {
        bf16x8 b[4], a[4];
        #pragma unroll
        for (int nt = 0; nt < 4; nt++) b[nt] = ldfrag(bp[nt] + k);
        #pragma unroll
        for (int mt = 0; mt < 4; mt++) a[mt] = ldfrag(ap[mt] + k);
        #pragma unroll
        for (int mt = 0; mt < 4; mt++)
            #pragma unroll
            for (int nt = 0; nt < 4; nt++)
                acc[mt][nt] = mfma16(a[mt], b[nt], acc[mt][nt]);
        if (PASSES == 2) {
            bf16x8 al2[4];
            #pragma unroll
            for (int mt = 0; mt < 4; mt++) al2[mt] = ldfrag(alp[mt] + k);
            #pragma unroll
            for (int mt = 0; mt < 4; mt++)
                #pragma unroll
                for (int nt = 0; nt < 4; nt++)
                    acc[mt][nt] = mfma16(al2[mt], b[nt], acc[mt][nt]);
        }
    }
    float bv[4];
    #pragma unroll
    for (int nt = 0; nt < 4; nt++) bv[nt] = bias[bn + wn * 64 + nt * 16 + l15];
    #pragma unroll
    for (int mt = 0; mt < 4; mt++) {
        int r0 = bm + wm * 64 + mt * 16 + lq * 4;
        #pragma unroll
        for (int nt = 0; nt < 4; nt++) {
            int col = bn + wn * 64 + nt * 16 + l15;
            if (OUTMODE == 0) {
                #pragma unroll
                for (int rr = 0; rr < 4; rr++)
                    ((u16*)Cout)[(size_t)(r0 + rr) * Dd + col] = f2bf(acc[mt][nt][rr] + bv[nt]);
            } else if (OUTMODE == 1) {
                int hh = col >> 6, dd = col & 63, b_ = r0 >> 11, s0 = r0 & 2047;
                u16 e0 = f2bf(acc[mt][nt][0] + bv[nt]), e1 = f2bf(acc[mt][nt][1] + bv[nt]);
                u16 e2 = f2bf(acc[mt][nt][2] + bv[nt]), e3 = f2bf(acc[mt][nt][3] + bv[nt]);
                uint2 pk = { (unsigned)e0 | ((unsigned)e1 << 16), (unsigned)e2 | ((unsigned)e3 << 16) };
                *(uint2*)((u16*)Cout + (size_t)((b_ * Hh + hh) * 64 + dd) * Ss + s0) = pk;
            } else {
                #pragma unroll
                for (int rr = 0; rr < 4; rr++)
                    ((float*)Cout)[(size_t)(r0 + rr) * Dd + col] = acc[mt][nt][rr] + bv[nt];
            }
        }
    }
}

// ---------------- MFMA flash attention v2: un-shifted softmax, no in-loop shuffles ----------------
// grid (S/64, H, B); 256 thr = 4 waves; wave owns 16 q-rows. K/V frags direct from global.
// p = exp(s)*mask (scores bounded ~50; masked -> exactly 0, matching ref's exp(-1e9-max)).
// Denominator: per-lane partial over this lane's key residues, one cross-lane reduce at end.
__global__ __launch_bounds__(256) void attn_mfma(
    u16* qctx, const u16* __restrict__ Kb, const u16* __restrict__ Vt,
    const float* __restrict__ maskf)
{
    __shared__ u16 Ps[4][16][76];            // stride 38 dwords: write row-groups on disjoint bank octets
    const int tid = threadIdx.x, lane = tid & 63, wave = tid >> 6;
    const int l15 = lane & 15, lq = lane >> 4;
    const int q0 = blockIdx.x * 64, h = blockIdx.y, b = blockIdx.z;
    const int qrow = q0 + wave * 16;

    const u16* qp = qctx + (size_t)(b * Ss + qrow + l15) * Dd + h * 64 + lq * 8;
    const bf16x8 qf0 = ldfrag(qp), qf1 = ldfrag(qp + 32);

    float li[4] = {0.f, 0.f, 0.f, 0.f};
    f32x4 acc[4] = {};

    const u16* pp0 = &Ps[wave][l15][lq * 8];
    const u16* pp1 = &Ps[wave][l15][32 + lq * 8];
    const u16* vbase = Vt + (size_t)((b * Hh + h) * 64 + l15) * Ss + lq * 8;

    for (int k0 = 0; k0 < Ss; k0 += 64) {
        const u16* kbase = Kb + (size_t)(b * Ss + k0 + l15) * Dd + h * 64 + lq * 8;
        bf16x8 kf[4][2];
        float mf[4];
        #pragma unroll
        for (int nt = 0; nt < 4; nt++) {
            kf[nt][0] = ldfrag(kbase + (size_t)nt * 16 * Dd);
            kf[nt][1] = ldfrag(kbase + (size_t)nt * 16 * Dd + 32);
            mf[nt] = maskf[b * Ss + k0 + nt * 16 + l15];
        }
        #pragma unroll
        for (int nt = 0; nt < 4; nt++) {
            f32x4 st = {};
            st = mfma16(qf0, kf[nt][0], st);
            st = mfma16(qf1, kf[nt][1], st);
            #pragma unroll
            for (int r = 0; r < 4; r++) {
                float p = __expf(st[r]) * mf[nt];      // masked -> 0
                li[r] += p;
                Ps[wave][lq * 4 + r][nt * 16 + l15] = f2bf(p);
            }
        }
        bf16x8 pf0 = ldfrag(pp0), pf1 = ldfrag(pp1);   // compiler inserts lgkmcnt wait
        #pragma unroll
        for (int dt = 0; dt < 4; dt++) {
            bf16x8 vf0 = ldfrag(vbase + (size_t)dt * 16 * Ss + k0);
            bf16x8 vf1 = ldfrag(vbase + (size_t)dt * 16 * Ss + k0 + 32);
            acc[dt] = mfma16(pf0, vf0, acc[dt]);
            acc[dt] = mfma16(pf1, vf1, acc[dt]);
        }
    }
    // epilogue: reduce denominators across the 16 key-residue lanes, normalize, q-mask, store
    #pragma unroll
    for (int r = 0; r < 4; r++) {
        float s = li[r];
        s += __shfl_xor(s, 1); s += __shfl_xor(s, 2);
        s += __shfl_xor(s, 4); s += __shfl_xor(s, 8);
        li[r] = s;
    }
    #pragma unroll
    for (int r = 0; r < 4; r++) {
        int q = q0 + wave * 16 + lq * 4 + r;
        float qm = maskf[b * Ss + q];
        float rl = li[r] > 0.f ? qm / li[r] : 0.f;
        #pragma unroll
        for (int dt = 0; dt < 4; dt++)
            qctx[(size_t)(b * Ss + q) * Dd + h * 64 + dt * 16 + l15] = f2bf(acc[dt][r] * rl);
    }
}

extern "C" void kernel_launch(void* const* d_in, const int* in_sizes, int n_in,
                              void* d_out, int out_size, void* d_ws, size_t ws_size,
                              hipStream_t stream) {
    const float* X  = (const float*)d_in[0];
    const unsigned char* mr = (const unsigned char*)d_in[1];
    const float* Wq = (const float*)d_in[2];
    const float* bq = (const float*)d_in[3];
    const float* Wk = (const float*)d_in[4];
    const float* bk = (const float*)d_in[5];
    const float* Wv = (const float*)d_in[6];
    const float* bv = (const float*)d_in[7];
    const float* Wo = (const float*)d_in[8];
    const float* bo = (const float*)d_in[9];
    float* out = (float*)d_out;

    // ws (64 MB)
    u16* wsb = (u16*)d_ws;
    u16* Xh  = wsb;                // dies after V-gemm; Wo^T overlays
    u16* Qb  = wsb + (size_t)SZt;  // ctx aliases after attention
    u16* Kb  = wsb + 2 * (size_t)SZt;
    u16* Vt  = wsb + 3 * (size_t)SZt;
    u16* Wot = Xh;
    // d_out scratch (first 22 MB; all dead before final GEMM writes d_out)
    u16* ob  = (u16*)d_out;
    u16* Xl  = ob;
    u16* Wqt = ob + (size_t)SZt;
    u16* Wkt = Wqt + 1048576;
    u16* Wvt = Wkt + 1048576;
    float* mnorm = (float*)(Wvt + 1048576);

    dim3 tg(32, 32), tb(32, 8);
    dim3 gg(Dd / 128, (Bb * Ss) / 128);        // (8, 64)

    normalize_mask<<<1, 1024, 0, stream>>>(mr, mnorm, Bb * Ss);
    convert_x<<<SZt / 1024, 256, 0, stream>>>(X, Xh, Xl);
    transpose_w<<<tg, tb, 0, stream>>>(Wq, Wqt);
    transpose_w<<<tg, tb, 0, stream>>>(Wk, Wkt);
    transpose_w<<<tg, tb, 0, stream>>>(Wv, Wvt);
    gemm_mfma<2, 0><<<gg, 256, 0, stream>>>(Xh, Xl, Wqt, bq, Qb);
    gemm_mfma<2, 0><<<gg, 256, 0, stream>>>(Xh, Xl, Wkt, bk, Kb);
    gemm_mfma<1, 1><<<gg, 256, 0, stream>>>(Xh, nullptr, Wvt, bv, Vt);
    transpose_w<<<tg, tb, 0, stream>>>(Wo, Wot);               // Xh dead -> reuse
    attn_mfma<<<dim3(Ss / 64, Hh, Bb), 256, 0, stream>>>(Qb, Kb, Vt, mnorm);
    gemm_mfma<1, 2><<<gg, 256, 0, stream>>>(Qb, nullptr, Wot, bo, out);
}

// Round 7
// 531.544 us; speedup vs baseline: 1.6784x; 1.6784x over previous
//
#include <hip/hip_runtime.h>

// B=4, S=2048, D=1024, H=16, head_dim=64. Inputs fp32, output fp32.
// MFMA bf16 pipeline; fp32 accumulate. 2-pass split-bf16 for Q/K projections.
// Attention v3: 32x32x16 MFMA, cooperative LDS staging (m97 2-barrier), Q-tile 256,
// un-shifted softmax (scores bounded ~50), per-lane denominators, epilogue reduce.
// ws (64MB): Xh[16] | Qb/ctx[16] | Kb[16] | Vt[16]  (Wo^T overlays Xh after its death)
// d_out (32MB) pre-final scratch: Xl[16] | Wqt[2] | Wkt[2] | Wvt[2] | mask_f32[32KB]

#define Bb 4
#define Ss 2048
#define Dd 1024
#define Hh 16
#define SZt 8388608

typedef short bf16x8 __attribute__((ext_vector_type(8)));
typedef float f32x4 __attribute__((ext_vector_type(4)));
typedef float f32x16 __attribute__((ext_vector_type(16)));
typedef unsigned short u16;

__device__ __forceinline__ float bf2f(u16 u) {
    return __builtin_bit_cast(float, ((unsigned)u) << 16);
}
__device__ __forceinline__ u16 f2bf(float f) {
    unsigned u = __builtin_bit_cast(unsigned, f);
    unsigned r = 0x7FFFu + ((u >> 16) & 1u);
    return (u16)((u + r) >> 16);
}
__device__ __forceinline__ bf16x8 ldfrag(const u16* p) {
    return __builtin_bit_cast(bf16x8, *(const uint4*)p);
}
__device__ __forceinline__ f32x4 mfma16(bf16x8 a, bf16x8 b, f32x4 c) {
    return __builtin_amdgcn_mfma_f32_16x16x32_bf16(a, b, c, 0, 0, 0);
}
__device__ __forceinline__ f32x16 mfma32(bf16x8 a, bf16x8 b, f32x16 c) {
    return __builtin_amdgcn_mfma_f32_32x32x16_bf16(a, b, c, 0, 0, 0);
}

// ---------------- mask normalization (dtype auto-detect; verified) -> float 0/1 ----------------
__global__ void normalize_mask(const unsigned char* __restrict__ raw, float* __restrict__ out, int n) {
    __shared__ int flags;
    if (threadIdx.x == 0) flags = 0;
    __syncthreads();
    int f = 0;
    for (int i = threadIdx.x; i < n; i += blockDim.x) {
        unsigned char c = raw[i];
        if ((i & 3) != 0 && c) f |= 1;
        if ((i & 3) == 1 && c >= 2) f |= 2;
        if ((i & 3) == 3 && c >= 2) f |= 4;
    }
    if (f) atomicOr(&flags, f);
    __syncthreads();
    int fl = flags;
    int layout;                 // 0=int32, 1=u8, 2=bf16, 3=f32
    if (!(fl & 1)) layout = 0;
    else if (fl & 2) layout = 2;
    else if (fl & 4) layout = 3;
    else layout = 1;
    for (int i = threadIdx.x; i < n; i += blockDim.x) {
        int v;
        if (layout == 0)      v = ((const int*)raw)[i];
        else if (layout == 1) v = raw[i];
        else if (layout == 2) v = ((const u16*)raw)[i] != 0;
        else                  v = ((const unsigned*)raw)[i] != 0;
        out[i] = (v != 0) ? 1.0f : 0.0f;
    }
}

// ---------------- X fp32 -> hi/lo bf16 split ----------------
__global__ __launch_bounds__(256) void convert_x(const float* __restrict__ X,
                                                 u16* __restrict__ Xh, u16* __restrict__ Xl) {
    size_t i = ((size_t)blockIdx.x * 256 + threadIdx.x) * 4;
    float4 v = *(const float4*)(X + i);
    u16 h0 = f2bf(v.x), h1 = f2bf(v.y), h2 = f2bf(v.z), h3 = f2bf(v.w);
    u16 l0 = f2bf(v.x - bf2f(h0)), l1 = f2bf(v.y - bf2f(h1));
    u16 l2 = f2bf(v.z - bf2f(h2)), l3 = f2bf(v.w - bf2f(h3));
    uint2 ph = { (unsigned)h0 | ((unsigned)h1 << 16), (unsigned)h2 | ((unsigned)h3 << 16) };
    uint2 pl = { (unsigned)l0 | ((unsigned)l1 << 16), (unsigned)l2 | ((unsigned)l3 << 16) };
    *(uint2*)(Xh + i) = ph;
    *(uint2*)(Xl + i) = pl;
}

// ---------------- W [K][N] fp32 -> Wt [N][K] bf16 (tiled transpose) ----------------
__global__ __launch_bounds__(256) void transpose_w(const float* __restrict__ W, u16* __restrict__ Wt) {
    __shared__ float t[32][33];
    const int tx = threadIdx.x, ty = threadIdx.y;
    const int n0 = blockIdx.x * 32, k0 = blockIdx.y * 32;
    #pragma unroll
    for (int i = 0; i < 4; i++)
        t[ty + i * 8][tx] = W[(size_t)(k0 + ty + i * 8) * Dd + n0 + tx];
    __syncthreads();
    #pragma unroll
    for (int i = 0; i < 4; i++)
        Wt[(size_t)(n0 + ty + i * 8) * Dd + k0 + tx] = f2bf(t[tx][ty + i * 8]);
}

// ---------------- MFMA GEMM, no LDS: C[8192,1024] = A[8192,1024] @ Wt^T + bias ----------------
template <int PASSES, int OUTMODE>
__global__ __launch_bounds__(256) void gemm_mfma(
    const u16* __restrict__ Ah, const u16* __restrict__ Al,
    const u16* __restrict__ Wt, const float* __restrict__ bias,
    void* __restrict__ Cout)
{
    const int tid = threadIdx.x, lane = tid & 63, wave = tid >> 6;
    const int wm = wave >> 1, wn = wave & 1;
    const int bm = blockIdx.y * 128, bn = blockIdx.x * 128;
    const int l15 = lane & 15, lq = lane >> 4;
    f32x4 acc[4][4] = {};
    const u16 *ap[4], *alp[4], *bp[4];
    #pragma unroll
    for (int mt = 0; mt < 4; mt++) {
        size_t row = bm + wm * 64 + mt * 16 + l15;
        ap[mt] = Ah + row * Dd + lq * 8;
        if (PASSES == 2) alp[mt] = Al + row * Dd + lq * 8;
    }
    #pragma unroll
    for (int nt = 0; nt < 4; nt++) {
        size_t col = bn + wn * 64 + nt * 16 + l15;
        bp[nt] = Wt + col * Dd + lq * 8;
    }
    #pragma unroll 2
    for (int k = 0; k < Dd; k += 32) {
        bf16x8 b[4], a[4];
        #pragma unroll
        for (int nt = 0; nt < 4; nt++) b[nt] = ldfrag(bp[nt] + k);
        #pragma unroll
        for (int mt = 0; mt < 4; mt++) a[mt] = ldfrag(ap[mt] + k);
        #pragma unroll
        for (int mt = 0; mt < 4; mt++)
            #pragma unroll
            for (int nt = 0; nt < 4; nt++)
                acc[mt][nt] = mfma16(a[mt], b[nt], acc[mt][nt]);
        if (PASSES == 2) {
            bf16x8 al2[4];
            #pragma unroll
            for (int mt = 0; mt < 4; mt++) al2[mt] = ldfrag(alp[mt] + k);
            #pragma unroll
            for (int mt = 0; mt < 4; mt++)
                #pragma unroll
                for (int nt = 0; nt < 4; nt++)
                    acc[mt][nt] = mfma16(al2[mt], b[nt], acc[mt][nt]);
        }
    }
    float bv[4];
    #pragma unroll
    for (int nt = 0; nt < 4; nt++) bv[nt] = bias[bn + wn * 64 + nt * 16 + l15];
    #pragma unroll
    for (int mt = 0; mt < 4; mt++) {
        int r0 = bm + wm * 64 + mt * 16 + lq * 4;
        #pragma unroll
        for (int nt = 0; nt < 4; nt++) {
            int col = bn + wn * 64 + nt * 16 + l15;
            if (OUTMODE == 0) {
                #pragma unroll
                for (int rr = 0; rr < 4; rr++)
                    ((u16*)Cout)[(size_t)(r0 + rr) * Dd + col] = f2bf(acc[mt][nt][rr] + bv[nt]);
            } else if (OUTMODE == 1) {
                int hh = col >> 6, dd = col & 63, b_ = r0 >> 11, s0 = r0 & 2047;
                u16 e0 = f2bf(acc[mt][nt][0] + bv[nt]), e1 = f2bf(acc[mt][nt][1] + bv[nt]);
                u16 e2 = f2bf(acc[mt][nt][2] + bv[nt]), e3 = f2bf(acc[mt][nt][3] + bv[nt]);
                uint2 pk = { (unsigned)e0 | ((unsigned)e1 << 16), (unsigned)e2 | ((unsigned)e3 << 16) };
                *(uint2*)((u16*)Cout + (size_t)((b_ * Hh + hh) * 64 + dd) * Ss + s0) = pk;
            } else {
                #pragma unroll
                for (int rr = 0; rr < 4; rr++)
                    ((float*)Cout)[(size_t)(r0 + rr) * Dd + col] = acc[mt][nt][rr] + bv[nt];
            }
        }
    }
}

// ---------------- MFMA flash attention v3: 32x32 tiles, staged LDS, 2-barrier ----------------
// grid (S/256, H, B); 512 thr = 8 waves; wave owns 32 q-rows.
// C/D layout 32x32 (m74/m101): col=lane&31, row=(reg&3)+8*(reg>>2)+4*(lane>>5).
// A/B frag: X[m|n=lane&31][k=(lane>>5)*8+j].
__global__ __launch_bounds__(512, 4) void attn_mfma(
    u16* qctx, const u16* __restrict__ Kb, const u16* __restrict__ Vt,
    const float* __restrict__ maskf)
{
    __shared__ u16 Ks[64][72];       // [key][d], stride 144B (16B-aligned)
    __shared__ u16 Vs[64][72];       // [d][key]
    __shared__ u16 Ps[8][32][72];    // per-wave P tile [qrow][key]
    const int tid = threadIdx.x, lane = tid & 63, wave = tid >> 6;
    const int l31 = lane & 31, hi = lane >> 5;
    const int q0 = blockIdx.x * 256, h = blockIdx.y, b = blockIdx.z;

    // Q A-frags (4 k-frags over d=64)
    bf16x8 qa[4];
    {
        const u16* qp = qctx + (size_t)(b * Ss + q0 + wave * 32 + l31) * Dd + h * 64 + hi * 8;
        #pragma unroll
        for (int kf = 0; kf < 4; kf++) qa[kf] = ldfrag(qp + kf * 16);
    }

    // staging maps: thread loads 16B of K and 16B of V per chunk
    const int srow = tid >> 3, scol = (tid & 7) * 8;
    const u16* kgsrc = Kb + (size_t)(b * Ss + srow) * Dd + h * 64 + scol;
    const u16* vgsrc = Vt + (size_t)((b * Hh + h) * 64 + srow) * Ss + scol;
    u16* kdst = &Ks[srow][scol];
    u16* vdst = &Vs[srow][scol];

    f32x16 acc0 = {}, acc1 = {};
    float li[16];
    #pragma unroll
    for (int r = 0; r < 16; r++) li[r] = 0.f;

    uint4 kreg = *(const uint4*)kgsrc;
    uint4 vreg = *(const uint4*)vgsrc;

    for (int k0 = 0; k0 < Ss; k0 += 64) {
        __syncthreads();                       // previous chunk fully consumed
        *(uint4*)kdst = kreg;
        *(uint4*)vdst = vreg;
        __syncthreads();
        int k0n = (k0 + 64 < Ss) ? k0 + 64 : 0;    // prefetch next chunk (redundant last iter)
        kreg = *(const uint4*)(kgsrc + (size_t)k0n * Dd);
        vreg = *(const uint4*)(vgsrc + k0n);

        // QK^T + unshifted softmax, nt-sequential to bound register liveness
        #pragma unroll
        for (int nt = 0; nt < 2; nt++) {
            f32x16 sc = {};
            #pragma unroll
            for (int kf = 0; kf < 4; kf++) {
                bf16x8 kb = ldfrag(&Ks[nt * 32 + l31][kf * 16 + hi * 8]);
                sc = mfma32(qa[kf], kb, sc);
            }
            float mf = maskf[b * Ss + k0 + nt * 32 + l31];
            #pragma unroll
            for (int r = 0; r < 16; r++) {
                float p = __expf(sc[r]) * mf;      // masked -> exactly 0
                li[r] += p;
                Ps[wave][(r & 3) + 8 * (r >> 2) + 4 * hi][nt * 32 + l31] = f2bf(p);
            }
        }
        // P @ V
        #pragma unroll
        for (int kf = 0; kf < 4; kf++) {
            bf16x8 pa = ldfrag(&Ps[wave][l31][kf * 16 + hi * 8]);
            bf16x8 v0 = ldfrag(&Vs[l31][kf * 16 + hi * 8]);
            bf16x8 v1 = ldfrag(&Vs[32 + l31][kf * 16 + hi * 8]);
            acc0 = mfma32(pa, v0, acc0);
            acc1 = mfma32(pa, v1, acc1);
        }
    }

    // epilogue: reduce denominators across the 32 key-lanes (bit5=hi preserved), normalize, store
    #pragma unroll
    for (int r = 0; r < 16; r++) {
        float s = li[r];
        s += __shfl_xor(s, 1); s += __shfl_xor(s, 2);
        s += __shfl_xor(s, 4); s += __shfl_xor(s, 8);
        s += __shfl_xor(s, 16);
        li[r] = s;
    }
    #pragma unroll
    for (int r = 0; r < 16; r++) {
        int row = (r & 3) + 8 * (r >> 2) + 4 * hi;
        int q = q0 + wave * 32 + row;
        float qm = maskf[b * Ss + q];
        float rl = li[r] > 0.f ? qm / li[r] : 0.f;
        u16* op = qctx + (size_t)(b * Ss + q) * Dd + h * 64 + l31;
        op[0]  = f2bf(acc0[r] * rl);
        op[32] = f2bf(acc1[r] * rl);
    }
}

extern "C" void kernel_launch(void* const* d_in, const int* in_sizes, int n_in,
                              void* d_out, int out_size, void* d_ws, size_t ws_size,
                              hipStream_t stream) {
    const float* X  = (const float*)d_in[0];
    const unsigned char* mr = (const unsigned char*)d_in[1];
    const float* Wq = (const float*)d_in[2];
    const float* bq = (const float*)d_in[3];
    const float* Wk = (const float*)d_in[4];
    const float* bk = (const float*)d_in[5];
    const float* Wv = (const float*)d_in[6];
    const float* bv = (const float*)d_in[7];
    const float* Wo = (const float*)d_in[8];
    const float* bo = (const float*)d_in[9];
    float* out = (float*)d_out;

    // ws (64 MB)
    u16* wsb = (u16*)d_ws;
    u16* Xh  = wsb;                // dies after V-gemm; Wo^T overlays
    u16* Qb  = wsb + (size_t)SZt;  // ctx aliases after attention
    u16* Kb  = wsb + 2 * (size_t)SZt;
    u16* Vt  = wsb + 3 * (size_t)SZt;
    u16* Wot = Xh;
    // d_out scratch (first 22 MB; all dead before final GEMM writes d_out)
    u16* ob  = (u16*)d_out;
    u16* Xl  = ob;
    u16* Wqt = ob + (size_t)SZt;
    u16* Wkt = Wqt + 1048576;
    u16* Wvt = Wkt + 1048576;
    float* mnorm = (float*)(Wvt + 1048576);

    dim3 tg(32, 32), tb(32, 8);
    dim3 gg(Dd / 128, (Bb * Ss) / 128);        // (8, 64)

    normalize_mask<<<1, 1024, 0, stream>>>(mr, mnorm, Bb * Ss);
    convert_x<<<SZt / 1024, 256, 0, stream>>>(X, Xh, Xl);
    transpose_w<<<tg, tb, 0, stream>>>(Wq, Wqt);
    transpose_w<<<tg, tb, 0, stream>>>(Wk, Wkt);
    transpose_w<<<tg, tb, 0, stream>>>(Wv, Wvt);
    gemm_mfma<2, 0><<<gg, 256, 0, stream>>>(Xh, Xl, Wqt, bq, Qb);
    gemm_mfma<2, 0><<<gg, 256, 0, stream>>>(Xh, Xl, Wkt, bk, Kb);
    gemm_mfma<1, 1><<<gg, 256, 0, stream>>>(Xh, nullptr, Wvt, bv, Vt);
    transpose_w<<<tg, tb, 0, stream>>>(Wo, Wot);               // Xh dead -> reuse
    attn_mfma<<<dim3(Ss / 256, Hh, Bb), 512, 0, stream>>>(Qb, Kb, Vt, mnorm);
    gemm_mfma<1, 2><<<gg, 256, 0, stream>>>(Qb, nullptr, Wot, bo, out);
}

// Round 8
// 376.834 us; speedup vs baseline: 2.3675x; 1.4106x over previous
//
#include <hip/hip_runtime.h>

// B=4, S=2048, D=1024, H=16, head_dim=64. Inputs fp32, output fp32.
// MFMA bf16 pipeline; fp32 accumulate. 2-pass split-bf16 for Q/K projections.
// GEMMs: m97-style 128x128 tile, BK=64, global_load_lds(16B) staging, 2-barrier K-loop.
// Attention v3 (unchanged): 32x32x16 MFMA, cooperative LDS staging, un-shifted softmax.
// ws (64MB): Xh[16] | Qb/ctx[16] | Kb[16] | Vt[16]  (Wo^T overlays Xh after its death)
// d_out (32MB) pre-final scratch: Xl[16] | Wqt[2] | Wkt[2] | Wvt[2] | mask_f32[32KB]

#define Bb 4
#define Ss 2048
#define Dd 1024
#define Hh 16
#define SZt 8388608

typedef short bf16x8 __attribute__((ext_vector_type(8)));
typedef float f32x4 __attribute__((ext_vector_type(4)));
typedef float f32x16 __attribute__((ext_vector_type(16)));
typedef unsigned short u16;

__device__ __forceinline__ float bf2f(u16 u) {
    return __builtin_bit_cast(float, ((unsigned)u) << 16);
}
__device__ __forceinline__ u16 f2bf(float f) {
    unsigned u = __builtin_bit_cast(unsigned, f);
    unsigned r = 0x7FFFu + ((u >> 16) & 1u);
    return (u16)((u + r) >> 16);
}
__device__ __forceinline__ bf16x8 ldfrag(const u16* p) {
    return __builtin_bit_cast(bf16x8, *(const uint4*)p);
}
__device__ __forceinline__ f32x4 mfma16(bf16x8 a, bf16x8 b, f32x4 c) {
    return __builtin_amdgcn_mfma_f32_16x16x32_bf16(a, b, c, 0, 0, 0);
}
__device__ __forceinline__ f32x16 mfma32(bf16x8 a, bf16x8 b, f32x16 c) {
    return __builtin_amdgcn_mfma_f32_32x32x16_bf16(a, b, c, 0, 0, 0);
}
// async global->LDS, 16B/lane; LDS dest = wave-uniform base + lane*16 (m97 contract)
__device__ __forceinline__ void gl2lds16(const u16* g, u16* l) {
    __builtin_amdgcn_global_load_lds(
        (const __attribute__((address_space(1))) u16*)g,
        (__attribute__((address_space(3))) u16*)l, 16, 0, 0);
}

// ---------------- mask normalization (dtype auto-detect; verified) -> float 0/1 ----------------
__global__ void normalize_mask(const unsigned char* __restrict__ raw, float* __restrict__ out, int n) {
    __shared__ int flags;
    if (threadIdx.x == 0) flags = 0;
    __syncthreads();
    int f = 0;
    for (int i = threadIdx.x; i < n; i += blockDim.x) {
        unsigned char c = raw[i];
        if ((i & 3) != 0 && c) f |= 1;
        if ((i & 3) == 1 && c >= 2) f |= 2;
        if ((i & 3) == 3 && c >= 2) f |= 4;
    }
    if (f) atomicOr(&flags, f);
    __syncthreads();
    int fl = flags;
    int layout;                 // 0=int32, 1=u8, 2=bf16, 3=f32
    if (!(fl & 1)) layout = 0;
    else if (fl & 2) layout = 2;
    else if (fl & 4) layout = 3;
    else layout = 1;
    for (int i = threadIdx.x; i < n; i += blockDim.x) {
        int v;
        if (layout == 0)      v = ((const int*)raw)[i];
        else if (layout == 1) v = raw[i];
        else if (layout == 2) v = ((const u16*)raw)[i] != 0;
        else                  v = ((const unsigned*)raw)[i] != 0;
        out[i] = (v != 0) ? 1.0f : 0.0f;
    }
}

// ---------------- X fp32 -> hi/lo bf16 split ----------------
__global__ __launch_bounds__(256) void convert_x(const float* __restrict__ X,
                                                 u16* __restrict__ Xh, u16* __restrict__ Xl) {
    size_t i = ((size_t)blockIdx.x * 256 + threadIdx.x) * 4;
    float4 v = *(const float4*)(X + i);
    u16 h0 = f2bf(v.x), h1 = f2bf(v.y), h2 = f2bf(v.z), h3 = f2bf(v.w);
    u16 l0 = f2bf(v.x - bf2f(h0)), l1 = f2bf(v.y - bf2f(h1));
    u16 l2 = f2bf(v.z - bf2f(h2)), l3 = f2bf(v.w - bf2f(h3));
    uint2 ph = { (unsigned)h0 | ((unsigned)h1 << 16), (unsigned)h2 | ((unsigned)h3 << 16) };
    uint2 pl = { (unsigned)l0 | ((unsigned)l1 << 16), (unsigned)l2 | ((unsigned)l3 << 16) };
    *(uint2*)(Xh + i) = ph;
    *(uint2*)(Xl + i) = pl;
}

// ---------------- W [K][N] fp32 -> Wt [N][K] bf16 (tiled transpose) ----------------
__global__ __launch_bounds__(256) void transpose_w(const float* __restrict__ W, u16* __restrict__ Wt) {
    __shared__ float t[32][33];
    const int tx = threadIdx.x, ty = threadIdx.y;
    const int n0 = blockIdx.x * 32, k0 = blockIdx.y * 32;
    #pragma unroll
    for (int i = 0; i < 4; i++)
        t[ty + i * 8][tx] = W[(size_t)(k0 + ty + i * 8) * Dd + n0 + tx];
    __syncthreads();
    #pragma unroll
    for (int i = 0; i < 4; i++)
        Wt[(size_t)(n0 + ty + i * 8) * Dd + k0 + tx] = f2bf(t[tx][ty + i * 8]);
}

// ---------------- m97-style GEMM: C[8192,1024] = A[8192,1024] @ Wt^T + bias ----------------
// 128x128 tile, BK=64, 256 thr = 4 waves (2x2), global_load_lds staging, 2-barrier loop.
// PASSES: 1 = Ah only; 2 = Ah + Al (split-fp32 precision).
// OUTMODE: 0 = bf16 [M][N]; 1 = bf16 V-transposed [b][h][d][s]; 2 = fp32 [M][N].
template <int PASSES, int OUTMODE>
__global__ __launch_bounds__(256) void gemm_mfma(
    const u16* __restrict__ Ah, const u16* __restrict__ Al,
    const u16* __restrict__ Wt, const float* __restrict__ bias,
    void* __restrict__ Cout)
{
    __shared__ u16 Ahs[128][64];                       // unpadded: global_load_lds layout
    __shared__ u16 Bs[128][64];
    __shared__ u16 Als[(PASSES == 2) ? 128 : 8][64];
    const int tid = threadIdx.x, lane = tid & 63, wave = tid >> 6;
    const int wm = wave >> 1, wn = wave & 1;
    const int bm = blockIdx.y * 128, bn = blockIdx.x * 128;
    const int l15 = lane & 15, lq = lane >> 4;
    // staging map: wave covers rows wave*32 + j*8 .. +8 (j=0..3); lane -> row l>>3, col (l&7)*8
    const int sr = wave * 32 + (lane >> 3);
    const int sc = (lane & 7) * 8;
    const u16* agp = Ah + (size_t)(bm + sr) * Dd + sc;
    const u16* bgp = Wt + (size_t)(bn + sr) * Dd + sc;
    const u16* algp = (PASSES == 2) ? (Al + (size_t)(bm + sr) * Dd + sc) : agp;

    f32x4 acc[4][4] = {};

    for (int k0 = 0; k0 < Dd; k0 += 64) {
        __syncthreads();                               // previous tile fully consumed
        #pragma unroll
        for (int j = 0; j < 4; j++) {
            gl2lds16(agp + k0 + (size_t)j * 8 * Dd, &Ahs[wave * 32 + j * 8][0]);
            gl2lds16(bgp + k0 + (size_t)j * 8 * Dd, &Bs[wave * 32 + j * 8][0]);
            if constexpr (PASSES == 2)
                gl2lds16(algp + k0 + (size_t)j * 8 * Dd, &Als[wave * 32 + j * 8][0]);
        }
        __syncthreads();                               // drains vmcnt -> LDS visible
        #pragma unroll
        for (int kf = 0; kf < 2; kf++) {
            bf16x8 b[4], a[4];
            #pragma unroll
            for (int nt = 0; nt < 4; nt++)
                b[nt] = ldfrag(&Bs[wn * 64 + nt * 16 + l15][kf * 32 + lq * 8]);
            #pragma unroll
            for (int mt = 0; mt < 4; mt++)
                a[mt] = ldfrag(&Ahs[wm * 64 + mt * 16 + l15][kf * 32 + lq * 8]);
            #pragma unroll
            for (int mt = 0; mt < 4; mt++)
                #pragma unroll
                for (int nt = 0; nt < 4; nt++)
                    acc[mt][nt] = mfma16(a[mt], b[nt], acc[mt][nt]);
            if constexpr (PASSES == 2) {
                bf16x8 al2[4];
                #pragma unroll
                for (int mt = 0; mt < 4; mt++)
                    al2[mt] = ldfrag(&Als[wm * 64 + mt * 16 + l15][kf * 32 + lq * 8]);
                #pragma unroll
                for (int mt = 0; mt < 4; mt++)
                    #pragma unroll
                    for (int nt = 0; nt < 4; nt++)
                        acc[mt][nt] = mfma16(al2[mt], b[nt], acc[mt][nt]);
            }
        }
    }
    float bv[4];
    #pragma unroll
    for (int nt = 0; nt < 4; nt++) bv[nt] = bias[bn + wn * 64 + nt * 16 + l15];
    #pragma unroll
    for (int mt = 0; mt < 4; mt++) {
        int r0 = bm + wm * 64 + mt * 16 + lq * 4;
        #pragma unroll
        for (int nt = 0; nt < 4; nt++) {
            int col = bn + wn * 64 + nt * 16 + l15;
            if (OUTMODE == 0) {
                #pragma unroll
                for (int rr = 0; rr < 4; rr++)
                    ((u16*)Cout)[(size_t)(r0 + rr) * Dd + col] = f2bf(acc[mt][nt][rr] + bv[nt]);
            } else if (OUTMODE == 1) {
                int hh = col >> 6, dd = col & 63, b_ = r0 >> 11, s0 = r0 & 2047;
                u16 e0 = f2bf(acc[mt][nt][0] + bv[nt]), e1 = f2bf(acc[mt][nt][1] + bv[nt]);
                u16 e2 = f2bf(acc[mt][nt][2] + bv[nt]), e3 = f2bf(acc[mt][nt][3] + bv[nt]);
                uint2 pk = { (unsigned)e0 | ((unsigned)e1 << 16), (unsigned)e2 | ((unsigned)e3 << 16) };
                *(uint2*)((u16*)Cout + (size_t)((b_ * Hh + hh) * 64 + dd) * Ss + s0) = pk;
            } else {
                #pragma unroll
                for (int rr = 0; rr < 4; rr++)
                    ((float*)Cout)[(size_t)(r0 + rr) * Dd + col] = acc[mt][nt][rr] + bv[nt];
            }
        }
    }
}

// ---------------- MFMA flash attention v3 (unchanged from round 7) ----------------
__global__ __launch_bounds__(512, 4) void attn_mfma(
    u16* qctx, const u16* __restrict__ Kb, const u16* __restrict__ Vt,
    const float* __restrict__ maskf)
{
    __shared__ u16 Ks[64][72];
    __shared__ u16 Vs[64][72];
    __shared__ u16 Ps[8][32][72];
    const int tid = threadIdx.x, lane = tid & 63, wave = tid >> 6;
    const int l31 = lane & 31, hi = lane >> 5;
    const int q0 = blockIdx.x * 256, h = blockIdx.y, b = blockIdx.z;

    bf16x8 qa[4];
    {
        const u16* qp = qctx + (size_t)(b * Ss + q0 + wave * 32 + l31) * Dd + h * 64 + hi * 8;
        #pragma unroll
        for (int kf = 0; kf < 4; kf++) qa[kf] = ldfrag(qp + kf * 16);
    }

    const int srow = tid >> 3, scol = (tid & 7) * 8;
    const u16* kgsrc = Kb + (size_t)(b * Ss + srow) * Dd + h * 64 + scol;
    const u16* vgsrc = Vt + (size_t)((b * Hh + h) * 64 + srow) * Ss + scol;
    u16* kdst = &Ks[srow][scol];
    u16* vdst = &Vs[srow][scol];

    f32x16 acc0 = {}, acc1 = {};
    float li[16];
    #pragma unroll
    for (int r = 0; r < 16; r++) li[r] = 0.f;

    uint4 kreg = *(const uint4*)kgsrc;
    uint4 vreg = *(const uint4*)vgsrc;

    for (int k0 = 0; k0 < Ss; k0 += 64) {
        __syncthreads();
        *(uint4*)kdst = kreg;
        *(uint4*)vdst = vreg;
        __syncthreads();
        int k0n = (k0 + 64 < Ss) ? k0 + 64 : 0;
        kreg = *(const uint4*)(kgsrc + (size_t)k0n * Dd);
        vreg = *(const uint4*)(vgsrc + k0n);

        #pragma unroll
        for (int nt = 0; nt < 2; nt++) {
            f32x16 sc = {};
            #pragma unroll
            for (int kf = 0; kf < 4; kf++) {
                bf16x8 kb = ldfrag(&Ks[nt * 32 + l31][kf * 16 + hi * 8]);
                sc = mfma32(qa[kf], kb, sc);
            }
            float mf = maskf[b * Ss + k0 + nt * 32 + l31];
            #pragma unroll
            for (int r = 0; r < 16; r++) {
                float p = __expf(sc[r]) * mf;
                li[r] += p;
                Ps[wave][(r & 3) + 8 * (r >> 2) + 4 * hi][nt * 32 + l31] = f2bf(p);
            }
        }
        #pragma unroll
        for (int kf = 0; kf < 4; kf++) {
            bf16x8 pa = ldfrag(&Ps[wave][l31][kf * 16 + hi * 8]);
            bf16x8 v0 = ldfrag(&Vs[l31][kf * 16 + hi * 8]);
            bf16x8 v1 = ldfrag(&Vs[32 + l31][kf * 16 + hi * 8]);
            acc0 = mfma32(pa, v0, acc0);
            acc1 = mfma32(pa, v1, acc1);
        }
    }

    #pragma unroll
    for (int r = 0; r < 16; r++) {
        float s = li[r];
        s += __shfl_xor(s, 1); s += __shfl_xor(s, 2);
        s += __shfl_xor(s, 4); s += __shfl_xor(s, 8);
        s += __shfl_xor(s, 16);
        li[r] = s;
    }
    #pragma unroll
    for (int r = 0; r < 16; r++) {
        int row = (r & 3) + 8 * (r >> 2) + 4 * hi;
        int q = q0 + wave * 32 + row;
        float qm = maskf[b * Ss + q];
        float rl = li[r] > 0.f ? qm / li[r] : 0.f;
        u16* op = qctx + (size_t)(b * Ss + q) * Dd + h * 64 + l31;
        op[0]  = f2bf(acc0[r] * rl);
        op[32] = f2bf(acc1[r] * rl);
    }
}

extern "C" void kernel_launch(void* const* d_in, const int* in_sizes, int n_in,
                              void* d_out, int out_size, void* d_ws, size_t ws_size,
                              hipStream_t stream) {
    const float* X  = (const float*)d_in[0];
    const unsigned char* mr = (const unsigned char*)d_in[1];
    const float* Wq = (const float*)d_in[2];
    const float* bq = (const float*)d_in[3];
    const float* Wk = (const float*)d_in[4];
    const float* bk = (const float*)d_in[5];
    const float* Wv = (const float*)d_in[6];
    const float* bv = (const float*)d_in[7];
    const float* Wo = (const float*)d_in[8];
    const float* bo = (const float*)d_in[9];
    float* out = (float*)d_out;

    // ws (64 MB)
    u16* wsb = (u16*)d_ws;
    u16* Xh  = wsb;                // dies after V-gemm; Wo^T overlays
    u16* Qb  = wsb + (size_t)SZt;  // ctx aliases after attention
    u16* Kb  = wsb + 2 * (size_t)SZt;
    u16* Vt  = wsb + 3 * (size_t)SZt;
    u16* Wot = Xh;
    // d_out scratch (first 22 MB; all dead before final GEMM writes d_out)
    u16* ob  = (u16*)d_out;
    u16* Xl  = ob;
    u16* Wqt = ob + (size_t)SZt;
    u16* Wkt = Wqt + 1048576;
    u16* Wvt = Wkt + 1048576;
    float* mnorm = (float*)(Wvt + 1048576);

    dim3 tg(32, 32), tb(32, 8);
    dim3 gg(Dd / 128, (Bb * Ss) / 128);        // (8, 64)

    normalize_mask<<<1, 1024, 0, stream>>>(mr, mnorm, Bb * Ss);
    convert_x<<<SZt / 1024, 256, 0, stream>>>(X, Xh, Xl);
    transpose_w<<<tg, tb, 0, stream>>>(Wq, Wqt);
    transpose_w<<<tg, tb, 0, stream>>>(Wk, Wkt);
    transpose_w<<<tg, tb, 0, stream>>>(Wv, Wvt);
    gemm_mfma<2, 0><<<gg, 256, 0, stream>>>(Xh, Xl, Wqt, bq, Qb);
    gemm_mfma<2, 0><<<gg, 256, 0, stream>>>(Xh, Xl, Wkt, bk, Kb);
    gemm_mfma<1, 1><<<gg, 256, 0, stream>>>(Xh, nullptr, Wvt, bv, Vt);
    transpose_w<<<tg, tb, 0, stream>>>(Wo, Wot);               // Xh dead -> reuse
    attn_mfma<<<dim3(Ss / 256, Hh, Bb), 512, 0, stream>>>(Qb, Kb, Vt, mnorm);
    gemm_mfma<1, 2><<<gg, 256, 0, stream>>>(Qb, nullptr, Wot, bo, out);
}

// Round 9
// 348.585 us; speedup vs baseline: 2.5593x; 1.0810x over previous
//
#include <hip/hip_runtime.h>

// B=4, S=2048, D=1024, H=16, head_dim=64. Inputs fp32, output fp32.
// MFMA bf16 pipeline; fp32 accumulate. 2-pass split-bf16 for Q/K projections.
// Round 9: QKV projections fused into one N=3072 GEMM (3 blocks/CU, block-uniform
// routing + per-range 1/2-pass); attention grid swizzled (bh fast, qchunk slow)
// so the 8 K/V-sharing blocks land on one XCD's L2.
// ws (64MB): Xh[16] | Qb/ctx[16] | Kb[16] | Vt[16]  (Wo^T overlays Xh after its death)
// d_out (32MB) pre-final scratch: Xl[16] | Wcat=Wqt|Wkt|Wvt[6] | mask_f32[32KB] | bcat[12KB]

#define Bb 4
#define Ss 2048
#define Dd 1024
#define Hh 16
#define SZt 8388608

typedef short bf16x8 __attribute__((ext_vector_type(8)));
typedef float f32x4 __attribute__((ext_vector_type(4)));
typedef float f32x16 __attribute__((ext_vector_type(16)));
typedef unsigned short u16;

__device__ __forceinline__ float bf2f(u16 u) {
    return __builtin_bit_cast(float, ((unsigned)u) << 16);
}
__device__ __forceinline__ u16 f2bf(float f) {
    unsigned u = __builtin_bit_cast(unsigned, f);
    unsigned r = 0x7FFFu + ((u >> 16) & 1u);
    return (u16)((u + r) >> 16);
}
__device__ __forceinline__ bf16x8 ldfrag(const u16* p) {
    return __builtin_bit_cast(bf16x8, *(const uint4*)p);
}
__device__ __forceinline__ f32x4 mfma16(bf16x8 a, bf16x8 b, f32x4 c) {
    return __builtin_amdgcn_mfma_f32_16x16x32_bf16(a, b, c, 0, 0, 0);
}
__device__ __forceinline__ f32x16 mfma32(bf16x8 a, bf16x8 b, f32x16 c) {
    return __builtin_amdgcn_mfma_f32_32x32x16_bf16(a, b, c, 0, 0, 0);
}
// async global->LDS, 16B/lane; LDS dest = wave-uniform base + lane*16 (m97 contract)
__device__ __forceinline__ void gl2lds16(const u16* g, u16* l) {
    __builtin_amdgcn_global_load_lds(
        (const __attribute__((address_space(1))) u16*)g,
        (__attribute__((address_space(3))) u16*)l, 16, 0, 0);
}

// ---------------- mask normalization (dtype auto-detect; verified) -> float 0/1 ----------------
__global__ void normalize_mask(const unsigned char* __restrict__ raw, float* __restrict__ out, int n) {
    __shared__ int flags;
    if (threadIdx.x == 0) flags = 0;
    __syncthreads();
    int f = 0;
    for (int i = threadIdx.x; i < n; i += blockDim.x) {
        unsigned char c = raw[i];
        if ((i & 3) != 0 && c) f |= 1;
        if ((i & 3) == 1 && c >= 2) f |= 2;
        if ((i & 3) == 3 && c >= 2) f |= 4;
    }
    if (f) atomicOr(&flags, f);
    __syncthreads();
    int fl = flags;
    int layout;                 // 0=int32, 1=u8, 2=bf16, 3=f32
    if (!(fl & 1)) layout = 0;
    else if (fl & 2) layout = 2;
    else if (fl & 4) layout = 3;
    else layout = 1;
    for (int i = threadIdx.x; i < n; i += blockDim.x) {
        int v;
        if (layout == 0)      v = ((const int*)raw)[i];
        else if (layout == 1) v = raw[i];
        else if (layout == 2) v = ((const u16*)raw)[i] != 0;
        else                  v = ((const unsigned*)raw)[i] != 0;
        out[i] = (v != 0) ? 1.0f : 0.0f;
    }
}

// ---------------- bias concat [bq|bk|bv] -> bcat[3072] ----------------
__global__ void concat_bias(const float* __restrict__ a, const float* __restrict__ b,
                            const float* __restrict__ c, float* __restrict__ o) {
    int i = blockIdx.x * 256 + threadIdx.x;
    o[i] = (i < 1024) ? a[i] : ((i < 2048) ? b[i - 1024] : c[i - 2048]);
}

// ---------------- X fp32 -> hi/lo bf16 split ----------------
__global__ __launch_bounds__(256) void convert_x(const float* __restrict__ X,
                                                 u16* __restrict__ Xh, u16* __restrict__ Xl) {
    size_t i = ((size_t)blockIdx.x * 256 + threadIdx.x) * 4;
    float4 v = *(const float4*)(X + i);
    u16 h0 = f2bf(v.x), h1 = f2bf(v.y), h2 = f2bf(v.z), h3 = f2bf(v.w);
    u16 l0 = f2bf(v.x - bf2f(h0)), l1 = f2bf(v.y - bf2f(h1));
    u16 l2 = f2bf(v.z - bf2f(h2)), l3 = f2bf(v.w - bf2f(h3));
    uint2 ph = { (unsigned)h0 | ((unsigned)h1 << 16), (unsigned)h2 | ((unsigned)h3 << 16) };
    uint2 pl = { (unsigned)l0 | ((unsigned)l1 << 16), (unsigned)l2 | ((unsigned)l3 << 16) };
    *(uint2*)(Xh + i) = ph;
    *(uint2*)(Xl + i) = pl;
}

// ---------------- W [K][N] fp32 -> Wt [N][K] bf16 (tiled transpose) ----------------
__global__ __launch_bounds__(256) void transpose_w(const float* __restrict__ W, u16* __restrict__ Wt) {
    __shared__ float t[32][33];
    const int tx = threadIdx.x, ty = threadIdx.y;
    const int n0 = blockIdx.x * 32, k0 = blockIdx.y * 32;
    #pragma unroll
    for (int i = 0; i < 4; i++)
        t[ty + i * 8][tx] = W[(size_t)(k0 + ty + i * 8) * Dd + n0 + tx];
    __syncthreads();
    #pragma unroll
    for (int i = 0; i < 4; i++)
        Wt[(size_t)(n0 + ty + i * 8) * Dd + k0 + tx] = f2bf(t[tx][ty + i * 8]);
}

// ---------------- fused QKV GEMM: [Q|K|V][8192,1024] = X[8192,1024] @ Wcat^T + bcat ----------------
// N=3072, 128x128 tile, BK=64, global_load_lds staging, 2-barrier loop.
// Block-uniform: bn<2048 -> 2-pass (Xh+Xl); bn>=2048 -> 1-pass. Output routed per range.
__global__ __launch_bounds__(256) void gemm_qkv(
    const u16* __restrict__ Ah, const u16* __restrict__ Al,
    const u16* __restrict__ Wcat, const float* __restrict__ bcat,
    u16* __restrict__ Qb, u16* __restrict__ Kb, u16* __restrict__ Vt)
{
    __shared__ u16 Ahs[128][64];
    __shared__ u16 Bs[128][64];
    __shared__ u16 Als[128][64];
    const int tid = threadIdx.x, lane = tid & 63, wave = tid >> 6;
    const int wm = wave >> 1, wn = wave & 1;
    const int bm = blockIdx.y * 128, bn = blockIdx.x * 128;
    const bool twopass = (bn < 2048);
    const int l15 = lane & 15, lq = lane >> 4;
    const int sr = wave * 32 + (lane >> 3);
    const int sc = (lane & 7) * 8;
    const u16* agp = Ah + (size_t)(bm + sr) * Dd + sc;
    const u16* bgp = Wcat + (size_t)(bn + sr) * Dd + sc;
    const u16* algp = Al + (size_t)(bm + sr) * Dd + sc;

    f32x4 acc[4][4] = {};

    for (int k0 = 0; k0 < Dd; k0 += 64) {
        __syncthreads();
        #pragma unroll
        for (int j = 0; j < 4; j++) {
            gl2lds16(agp + k0 + (size_t)j * 8 * Dd, &Ahs[wave * 32 + j * 8][0]);
            gl2lds16(bgp + k0 + (size_t)j * 8 * Dd, &Bs[wave * 32 + j * 8][0]);
            if (twopass)
                gl2lds16(algp + k0 + (size_t)j * 8 * Dd, &Als[wave * 32 + j * 8][0]);
        }
        __syncthreads();
        #pragma unroll
        for (int kf = 0; kf < 2; kf++) {
            bf16x8 b[4], a[4];
            #pragma unroll
            for (int nt = 0; nt < 4; nt++)
                b[nt] = ldfrag(&Bs[wn * 64 + nt * 16 + l15][kf * 32 + lq * 8]);
            #pragma unroll
            for (int mt = 0; mt < 4; mt++)
                a[mt] = ldfrag(&Ahs[wm * 64 + mt * 16 + l15][kf * 32 + lq * 8]);
            #pragma unroll
            for (int mt = 0; mt < 4; mt++)
                #pragma unroll
                for (int nt = 0; nt < 4; nt++)
                    acc[mt][nt] = mfma16(a[mt], b[nt], acc[mt][nt]);
            if (twopass) {
                bf16x8 al2[4];
                #pragma unroll
                for (int mt = 0; mt < 4; mt++)
                    al2[mt] = ldfrag(&Als[wm * 64 + mt * 16 + l15][kf * 32 + lq * 8]);
                #pragma unroll
                for (int mt = 0; mt < 4; mt++)
                    #pragma unroll
                    for (int nt = 0; nt < 4; nt++)
                        acc[mt][nt] = mfma16(al2[mt], b[nt], acc[mt][nt]);
            }
        }
    }
    float bv[4];
    #pragma unroll
    for (int nt = 0; nt < 4; nt++) bv[nt] = bcat[bn + wn * 64 + nt * 16 + l15];
    #pragma unroll
    for (int mt = 0; mt < 4; mt++) {
        int r0 = bm + wm * 64 + mt * 16 + lq * 4;
        #pragma unroll
        for (int nt = 0; nt < 4; nt++) {
            int col = bn + wn * 64 + nt * 16 + l15;
            if (col < 1024) {                                  // Q
                #pragma unroll
                for (int rr = 0; rr < 4; rr++)
                    Qb[(size_t)(r0 + rr) * Dd + col] = f2bf(acc[mt][nt][rr] + bv[nt]);
            } else if (col < 2048) {                           // K
                int c2 = col - 1024;
                #pragma unroll
                for (int rr = 0; rr < 4; rr++)
                    Kb[(size_t)(r0 + rr) * Dd + c2] = f2bf(acc[mt][nt][rr] + bv[nt]);
            } else {                                           // V, transposed [b][h][d][s]
                int c2 = col - 2048;
                int hh = c2 >> 6, dd = c2 & 63, b_ = r0 >> 11, s0 = r0 & 2047;
                u16 e0 = f2bf(acc[mt][nt][0] + bv[nt]), e1 = f2bf(acc[mt][nt][1] + bv[nt]);
                u16 e2 = f2bf(acc[mt][nt][2] + bv[nt]), e3 = f2bf(acc[mt][nt][3] + bv[nt]);
                uint2 pk = { (unsigned)e0 | ((unsigned)e1 << 16), (unsigned)e2 | ((unsigned)e3 << 16) };
                *(uint2*)(Vt + (size_t)((b_ * Hh + hh) * 64 + dd) * Ss + s0) = pk;
            }
        }
    }
}

// ---------------- m97-style GEMM (output projection): fp32 out ----------------
__global__ __launch_bounds__(256) void gemm_out(
    const u16* __restrict__ Ah, const u16* __restrict__ Wt,
    const float* __restrict__ bias, float* __restrict__ Cout)
{
    __shared__ u16 Ahs[128][64];
    __shared__ u16 Bs[128][64];
    const int tid = threadIdx.x, lane = tid & 63, wave = tid >> 6;
    const int wm = wave >> 1, wn = wave & 1;
    const int bm = blockIdx.y * 128, bn = blockIdx.x * 128;
    const int l15 = lane & 15, lq = lane >> 4;
    const int sr = wave * 32 + (lane >> 3);
    const int sc = (lane & 7) * 8;
    const u16* agp = Ah + (size_t)(bm + sr) * Dd + sc;
    const u16* bgp = Wt + (size_t)(bn + sr) * Dd + sc;

    f32x4 acc[4][4] = {};

    for (int k0 = 0; k0 < Dd; k0 += 64) {
        __syncthreads();
        #pragma unroll
        for (int j = 0; j < 4; j++) {
            gl2lds16(agp + k0 + (size_t)j * 8 * Dd, &Ahs[wave * 32 + j * 8][0]);
            gl2lds16(bgp + k0 + (size_t)j * 8 * Dd, &Bs[wave * 32 + j * 8][0]);
        }
        __syncthreads();
        #pragma unroll
        for (int kf = 0; kf < 2; kf++) {
            bf16x8 b[4], a[4];
            #pragma unroll
            for (int nt = 0; nt < 4; nt++)
                b[nt] = ldfrag(&Bs[wn * 64 + nt * 16 + l15][kf * 32 + lq * 8]);
            #pragma unroll
            for (int mt = 0; mt < 4; mt++)
                a[mt] = ldfrag(&Ahs[wm * 64 + mt * 16 + l15][kf * 32 + lq * 8]);
            #pragma unroll
            for (int mt = 0; mt < 4; mt++)
                #pragma unroll
                for (int nt = 0; nt < 4; nt++)
                    acc[mt][nt] = mfma16(a[mt], b[nt], acc[mt][nt]);
        }
    }
    float bv[4];
    #pragma unroll
    for (int nt = 0; nt < 4; nt++) bv[nt] = bias[bn + wn * 64 + nt * 16 + l15];
    #pragma unroll
    for (int mt = 0; mt < 4; mt++) {
        int r0 = bm + wm * 64 + mt * 16 + lq * 4;
        #pragma unroll
        for (int nt = 0; nt < 4; nt++) {
            int col = bn + wn * 64 + nt * 16 + l15;
            #pragma unroll
            for (int rr = 0; rr < 4; rr++)
                Cout[(size_t)(r0 + rr) * Dd + col] = acc[mt][nt][rr] + bv[nt];
        }
    }
}

// ---------------- MFMA flash attention v4: XCD-swizzled grid ----------------
// grid (B*H, S/256): x = bh (fast) -> the 8 q-chunk blocks sharing a (b,h) K/V slice
// get linear ids === bh (mod 8) -> same XCD -> K/V served from that XCD's L2.
__global__ __launch_bounds__(512, 4) void attn_mfma(
    u16* qctx, const u16* __restrict__ Kb, const u16* __restrict__ Vt,
    const float* __restrict__ maskf)
{
    __shared__ u16 Ks[64][72];
    __shared__ u16 Vs[64][72];
    __shared__ u16 Ps[8][32][72];
    const int tid = threadIdx.x, lane = tid & 63, wave = tid >> 6;
    const int l31 = lane & 31, hi = lane >> 5;
    const int bh = blockIdx.x, h = bh & 15, b = bh >> 4;
    const int q0 = blockIdx.y * 256;

    bf16x8 qa[4];
    {
        const u16* qp = qctx + (size_t)(b * Ss + q0 + wave * 32 + l31) * Dd + h * 64 + hi * 8;
        #pragma unroll
        for (int kf = 0; kf < 4; kf++) qa[kf] = ldfrag(qp + kf * 16);
    }

    const int srow = tid >> 3, scol = (tid & 7) * 8;
    const u16* kgsrc = Kb + (size_t)(b * Ss + srow) * Dd + h * 64 + scol;
    const u16* vgsrc = Vt + (size_t)((b * Hh + h) * 64 + srow) * Ss + scol;
    u16* kdst = &Ks[srow][scol];
    u16* vdst = &Vs[srow][scol];

    f32x16 acc0 = {}, acc1 = {};
    float li[16];
    #pragma unroll
    for (int r = 0; r < 16; r++) li[r] = 0.f;

    uint4 kreg = *(const uint4*)kgsrc;
    uint4 vreg = *(const uint4*)vgsrc;

    for (int k0 = 0; k0 < Ss; k0 += 64) {
        __syncthreads();
        *(uint4*)kdst = kreg;
        *(uint4*)vdst = vreg;
        __syncthreads();
        int k0n = (k0 + 64 < Ss) ? k0 + 64 : 0;
        kreg = *(const uint4*)(kgsrc + (size_t)k0n * Dd);
        vreg = *(const uint4*)(vgsrc + k0n);

        #pragma unroll
        for (int nt = 0; nt < 2; nt++) {
            f32x16 sc = {};
            #pragma unroll
            for (int kf = 0; kf < 4; kf++) {
                bf16x8 kb = ldfrag(&Ks[nt * 32 + l31][kf * 16 + hi * 8]);
                sc = mfma32(qa[kf], kb, sc);
            }
            float mf = maskf[b * Ss + k0 + nt * 32 + l31];
            #pragma unroll
            for (int r = 0; r < 16; r++) {
                float p = __expf(sc[r]) * mf;
                li[r] += p;
                Ps[wave][(r & 3) + 8 * (r >> 2) + 4 * hi][nt * 32 + l31] = f2bf(p);
            }
        }
        #pragma unroll
        for (int kf = 0; kf < 4; kf++) {
            bf16x8 pa = ldfrag(&Ps[wave][l31][kf * 16 + hi * 8]);
            bf16x8 v0 = ldfrag(&Vs[l31][kf * 16 + hi * 8]);
            bf16x8 v1 = ldfrag(&Vs[32 + l31][kf * 16 + hi * 8]);
            acc0 = mfma32(pa, v0, acc0);
            acc1 = mfma32(pa, v1, acc1);
        }
    }

    #pragma unroll
    for (int r = 0; r < 16; r++) {
        float s = li[r];
        s += __shfl_xor(s, 1); s += __shfl_xor(s, 2);
        s += __shfl_xor(s, 4); s += __shfl_xor(s, 8);
        s += __shfl_xor(s, 16);
        li[r] = s;
    }
    #pragma unroll
    for (int r = 0; r < 16; r++) {
        int row = (r & 3) + 8 * (r >> 2) + 4 * hi;
        int q = q0 + wave * 32 + row;
        float qm = maskf[b * Ss + q];
        float rl = li[r] > 0.f ? qm / li[r] : 0.f;
        u16* op = qctx + (size_t)(b * Ss + q) * Dd + h * 64 + l31;
        op[0]  = f2bf(acc0[r] * rl);
        op[32] = f2bf(acc1[r] * rl);
    }
}

extern "C" void kernel_launch(void* const* d_in, const int* in_sizes, int n_in,
                              void* d_out, int out_size, void* d_ws, size_t ws_size,
                              hipStream_t stream) {
    const float* X  = (const float*)d_in[0];
    const unsigned char* mr = (const unsigned char*)d_in[1];
    const float* Wq = (const float*)d_in[2];
    const float* bq = (const float*)d_in[3];
    const float* Wk = (const float*)d_in[4];
    const float* bk = (const float*)d_in[5];
    const float* Wv = (const float*)d_in[6];
    const float* bv = (const float*)d_in[7];
    const float* Wo = (const float*)d_in[8];
    const float* bo = (const float*)d_in[9];
    float* out = (float*)d_out;

    // ws (64 MB)
    u16* wsb = (u16*)d_ws;
    u16* Xh  = wsb;                // dies after QKV-gemm; Wo^T overlays
    u16* Qb  = wsb + (size_t)SZt;  // ctx aliases after attention
    u16* Kb  = wsb + 2 * (size_t)SZt;
    u16* Vt  = wsb + 3 * (size_t)SZt;
    u16* Wot = Xh;
    // d_out scratch (first ~22 MB; all dead before final GEMM writes d_out)
    u16* ob  = (u16*)d_out;
    u16* Xl  = ob;
    u16* Wcat = ob + (size_t)SZt;              // Wqt|Wkt|Wvt contiguous = [3072][1024]
    u16* Wqt = Wcat;
    u16* Wkt = Wqt + 1048576;
    u16* Wvt = Wkt + 1048576;
    float* mnorm = (float*)(Wvt + 1048576);    // 32 KB
    float* bcat  = mnorm + Bb * Ss;            // 12 KB

    dim3 tg(32, 32), tb(32, 8);

    normalize_mask<<<1, 1024, 0, stream>>>(mr, mnorm, Bb * Ss);
    concat_bias<<<12, 256, 0, stream>>>(bq, bk, bv, bcat);
    convert_x<<<SZt / 1024, 256, 0, stream>>>(X, Xh, Xl);
    transpose_w<<<tg, tb, 0, stream>>>(Wq, Wqt);
    transpose_w<<<tg, tb, 0, stream>>>(Wk, Wkt);
    transpose_w<<<tg, tb, 0, stream>>>(Wv, Wvt);
    gemm_qkv<<<dim3(24, 64), 256, 0, stream>>>(Xh, Xl, Wcat, bcat, Qb, Kb, Vt);
    transpose_w<<<tg, tb, 0, stream>>>(Wo, Wot);               // Xh dead -> reuse
    attn_mfma<<<dim3(Bb * Hh, Ss / 256), 512, 0, stream>>>(Qb, Kb, Vt, mnorm);
    gemm_out<<<dim3(8, 64), 256, 0, stream>>>(Qb, Wot, bo, out);
}

// Round 10
// 333.363 us; speedup vs baseline: 2.6762x; 1.0457x over previous
//
#include <hip/hip_runtime.h>

// B=4, S=2048, D=1024, H=16, head_dim=64. Inputs fp32, output fp32.
// MFMA bf16 pipeline; fp32 accumulate. 2-pass split-bf16 for Q/K projections.
// Round 10: attention softmax path slimmed — mask folded into exp2-fma (mbias array),
// round-half-up P pack, PV split into 32-key halves (Ps reuse; PV overlaps next QK/exp).
// ws (64MB): Xh[16] | Qb/ctx[16] | Kb[16] | Vt[16]  (Wo^T overlays Xh after its death)
// d_out (32MB) pre-final scratch: Xl[16] | Wcat[6] | mnorm[32KB] | bcat[12KB] | mbias[32KB]

#define Bb 4
#define Ss 2048
#define Dd 1024
#define Hh 16
#define SZt 8388608

typedef short bf16x8 __attribute__((ext_vector_type(8)));
typedef float f32x4 __attribute__((ext_vector_type(4)));
typedef float f32x16 __attribute__((ext_vector_type(16)));
typedef unsigned short u16;

__device__ __forceinline__ float bf2f(u16 u) {
    return __builtin_bit_cast(float, ((unsigned)u) << 16);
}
__device__ __forceinline__ u16 f2bf(float f) {
    unsigned u = __builtin_bit_cast(unsigned, f);
    unsigned r = 0x7FFFu + ((u >> 16) & 1u);
    return (u16)((u + r) >> 16);
}
__device__ __forceinline__ bf16x8 ldfrag(const u16* p) {
    return __builtin_bit_cast(bf16x8, *(const uint4*)p);
}
__device__ __forceinline__ f32x4 mfma16(bf16x8 a, bf16x8 b, f32x4 c) {
    return __builtin_amdgcn_mfma_f32_16x16x32_bf16(a, b, c, 0, 0, 0);
}
__device__ __forceinline__ f32x16 mfma32(bf16x8 a, bf16x8 b, f32x16 c) {
    return __builtin_amdgcn_mfma_f32_32x32x16_bf16(a, b, c, 0, 0, 0);
}
// async global->LDS, 16B/lane; LDS dest = wave-uniform base + lane*16 (m97 contract)
__device__ __forceinline__ void gl2lds16(const u16* g, u16* l) {
    __builtin_amdgcn_global_load_lds(
        (const __attribute__((address_space(1))) u16*)g,
        (__attribute__((address_space(3))) u16*)l, 16, 0, 0);
}

// ---------------- mask normalization -> mnorm (0/1 float) + mbias (0 / -30000, log2-units) ----------------
__global__ void normalize_mask(const unsigned char* __restrict__ raw, float* __restrict__ out,
                               float* __restrict__ outb, int n) {
    __shared__ int flags;
    if (threadIdx.x == 0) flags = 0;
    __syncthreads();
    int f = 0;
    for (int i = threadIdx.x; i < n; i += blockDim.x) {
        unsigned char c = raw[i];
        if ((i & 3) != 0 && c) f |= 1;
        if ((i & 3) == 1 && c >= 2) f |= 2;
        if ((i & 3) == 3 && c >= 2) f |= 4;
    }
    if (f) atomicOr(&flags, f);
    __syncthreads();
    int fl = flags;
    int layout;                 // 0=int32, 1=u8, 2=bf16, 3=f32
    if (!(fl & 1)) layout = 0;
    else if (fl & 2) layout = 2;
    else if (fl & 4) layout = 3;
    else layout = 1;
    for (int i = threadIdx.x; i < n; i += blockDim.x) {
        int v;
        if (layout == 0)      v = ((const int*)raw)[i];
        else if (layout == 1) v = raw[i];
        else if (layout == 2) v = ((const u16*)raw)[i] != 0;
        else                  v = ((const unsigned*)raw)[i] != 0;
        out[i]  = (v != 0) ? 1.0f : 0.0f;
        outb[i] = (v != 0) ? 0.0f : -30000.0f;   // exp2(-30000+s) == 0 for |s|<=few hundred
    }
}

// ---------------- bias concat [bq|bk|bv] -> bcat[3072] ----------------
__global__ void concat_bias(const float* __restrict__ a, const float* __restrict__ b,
                            const float* __restrict__ c, float* __restrict__ o) {
    int i = blockIdx.x * 256 + threadIdx.x;
    o[i] = (i < 1024) ? a[i] : ((i < 2048) ? b[i - 1024] : c[i - 2048]);
}

// ---------------- X fp32 -> hi/lo bf16 split ----------------
__global__ __launch_bounds__(256) void convert_x(const float* __restrict__ X,
                                                 u16* __restrict__ Xh, u16* __restrict__ Xl) {
    size_t i = ((size_t)blockIdx.x * 256 + threadIdx.x) * 4;
    float4 v = *(const float4*)(X + i);
    u16 h0 = f2bf(v.x), h1 = f2bf(v.y), h2 = f2bf(v.z), h3 = f2bf(v.w);
    u16 l0 = f2bf(v.x - bf2f(h0)), l1 = f2bf(v.y - bf2f(h1));
    u16 l2 = f2bf(v.z - bf2f(h2)), l3 = f2bf(v.w - bf2f(h3));
    uint2 ph = { (unsigned)h0 | ((unsigned)h1 << 16), (unsigned)h2 | ((unsigned)h3 << 16) };
    uint2 pl = { (unsigned)l0 | ((unsigned)l1 << 16), (unsigned)l2 | ((unsigned)l3 << 16) };
    *(uint2*)(Xh + i) = ph;
    *(uint2*)(Xl + i) = pl;
}

// ---------------- W [K][N] fp32 -> Wt [N][K] bf16 (tiled transpose) ----------------
__global__ __launch_bounds__(256) void transpose_w(const float* __restrict__ W, u16* __restrict__ Wt) {
    __shared__ float t[32][33];
    const int tx = threadIdx.x, ty = threadIdx.y;
    const int n0 = blockIdx.x * 32, k0 = blockIdx.y * 32;
    #pragma unroll
    for (int i = 0; i < 4; i++)
        t[ty + i * 8][tx] = W[(size_t)(k0 + ty + i * 8) * Dd + n0 + tx];
    __syncthreads();
    #pragma unroll
    for (int i = 0; i < 4; i++)
        Wt[(size_t)(n0 + ty + i * 8) * Dd + k0 + tx] = f2bf(t[tx][ty + i * 8]);
}

// ---------------- fused QKV GEMM: [Q|K|V][8192,1024] = X[8192,1024] @ Wcat^T + bcat ----------------
__global__ __launch_bounds__(256) void gemm_qkv(
    const u16* __restrict__ Ah, const u16* __restrict__ Al,
    const u16* __restrict__ Wcat, const float* __restrict__ bcat,
    u16* __restrict__ Qb, u16* __restrict__ Kb, u16* __restrict__ Vt)
{
    __shared__ u16 Ahs[128][64];
    __shared__ u16 Bs[128][64];
    __shared__ u16 Als[128][64];
    const int tid = threadIdx.x, lane = tid & 63, wave = tid >> 6;
    const int wm = wave >> 1, wn = wave & 1;
    const int bm = blockIdx.y * 128, bn = blockIdx.x * 128;
    const bool twopass = (bn < 2048);
    const int l15 = lane & 15, lq = lane >> 4;
    const int sr = wave * 32 + (lane >> 3);
    const int sc = (lane & 7) * 8;
    const u16* agp = Ah + (size_t)(bm + sr) * Dd + sc;
    const u16* bgp = Wcat + (size_t)(bn + sr) * Dd + sc;
    const u16* algp = Al + (size_t)(bm + sr) * Dd + sc;

    f32x4 acc[4][4] = {};

    for (int k0 = 0; k0 < Dd; k0 += 64) {
        __syncthreads();
        #pragma unroll
        for (int j = 0; j < 4; j++) {
            gl2lds16(agp + k0 + (size_t)j * 8 * Dd, &Ahs[wave * 32 + j * 8][0]);
            gl2lds16(bgp + k0 + (size_t)j * 8 * Dd, &Bs[wave * 32 + j * 8][0]);
            if (twopass)
                gl2lds16(algp + k0 + (size_t)j * 8 * Dd, &Als[wave * 32 + j * 8][0]);
        }
        __syncthreads();
        #pragma unroll
        for (int kf = 0; kf < 2; kf++) {
            bf16x8 b[4], a[4];
            #pragma unroll
            for (int nt = 0; nt < 4; nt++)
                b[nt] = ldfrag(&Bs[wn * 64 + nt * 16 + l15][kf * 32 + lq * 8]);
            #pragma unroll
            for (int mt = 0; mt < 4; mt++)
                a[mt] = ldfrag(&Ahs[wm * 64 + mt * 16 + l15][kf * 32 + lq * 8]);
            #pragma unroll
            for (int mt = 0; mt < 4; mt++)
                #pragma unroll
                for (int nt = 0; nt < 4; nt++)
                    acc[mt][nt] = mfma16(a[mt], b[nt], acc[mt][nt]);
            if (twopass) {
                bf16x8 al2[4];
                #pragma unroll
                for (int mt = 0; mt < 4; mt++)
                    al2[mt] = ldfrag(&Als[wm * 64 + mt * 16 + l15][kf * 32 + lq * 8]);
                #pragma unroll
                for (int mt = 0; mt < 4; mt++)
                    #pragma unroll
                    for (int nt = 0; nt < 4; nt++)
                        acc[mt][nt] = mfma16(al2[mt], b[nt], acc[mt][nt]);
            }
        }
    }
    float bv[4];
    #pragma unroll
    for (int nt = 0; nt < 4; nt++) bv[nt] = bcat[bn + wn * 64 + nt * 16 + l15];
    #pragma unroll
    for (int mt = 0; mt < 4; mt++) {
        int r0 = bm + wm * 64 + mt * 16 + lq * 4;
        #pragma unroll
        for (int nt = 0; nt < 4; nt++) {
            int col = bn + wn * 64 + nt * 16 + l15;
            if (col < 1024) {                                  // Q
                #pragma unroll
                for (int rr = 0; rr < 4; rr++)
                    Qb[(size_t)(r0 + rr) * Dd + col] = f2bf(acc[mt][nt][rr] + bv[nt]);
            } else if (col < 2048) {                           // K
                int c2 = col - 1024;
                #pragma unroll
                for (int rr = 0; rr < 4; rr++)
                    Kb[(size_t)(r0 + rr) * Dd + c2] = f2bf(acc[mt][nt][rr] + bv[nt]);
            } else {                                           // V, transposed [b][h][d][s]
                int c2 = col - 2048;
                int hh = c2 >> 6, dd = c2 & 63, b_ = r0 >> 11, s0 = r0 & 2047;
                u16 e0 = f2bf(acc[mt][nt][0] + bv[nt]), e1 = f2bf(acc[mt][nt][1] + bv[nt]);
                u16 e2 = f2bf(acc[mt][nt][2] + bv[nt]), e3 = f2bf(acc[mt][nt][3] + bv[nt]);
                uint2 pk = { (unsigned)e0 | ((unsigned)e1 << 16), (unsigned)e2 | ((unsigned)e3 << 16) };
                *(uint2*)(Vt + (size_t)((b_ * Hh + hh) * 64 + dd) * Ss + s0) = pk;
            }
        }
    }
}

// ---------------- m97-style GEMM (output projection): fp32 out ----------------
__global__ __launch_bounds__(256) void gemm_out(
    const u16* __restrict__ Ah, const u16* __restrict__ Wt,
    const float* __restrict__ bias, float* __restrict__ Cout)
{
    __shared__ u16 Ahs[128][64];
    __shared__ u16 Bs[128][64];
    const int tid = threadIdx.x, lane = tid & 63, wave = tid >> 6;
    const int wm = wave >> 1, wn = wave & 1;
    const int bm = blockIdx.y * 128, bn = blockIdx.x * 128;
    const int l15 = lane & 15, lq = lane >> 4;
    const int sr = wave * 32 + (lane >> 3);
    const int sc = (lane & 7) * 8;
    const u16* agp = Ah + (size_t)(bm + sr) * Dd + sc;
    const u16* bgp = Wt + (size_t)(bn + sr) * Dd + sc;

    f32x4 acc[4][4] = {};

    for (int k0 = 0; k0 < Dd; k0 += 64) {
        __syncthreads();
        #pragma unroll
        for (int j = 0; j < 4; j++) {
            gl2lds16(agp + k0 + (size_t)j * 8 * Dd, &Ahs[wave * 32 + j * 8][0]);
            gl2lds16(bgp + k0 + (size_t)j * 8 * Dd, &Bs[wave * 32 + j * 8][0]);
        }
        __syncthreads();
        #pragma unroll
        for (int kf = 0; kf < 2; kf++) {
            bf16x8 b[4], a[4];
            #pragma unroll
            for (int nt = 0; nt < 4; nt++)
                b[nt] = ldfrag(&Bs[wn * 64 + nt * 16 + l15][kf * 32 + lq * 8]);
            #pragma unroll
            for (int mt = 0; mt < 4; mt++)
                a[mt] = ldfrag(&Ahs[wm * 64 + mt * 16 + l15][kf * 32 + lq * 8]);
            #pragma unroll
            for (int mt = 0; mt < 4; mt++)
                #pragma unroll
                for (int nt = 0; nt < 4; nt++)
                    acc[mt][nt] = mfma16(a[mt], b[nt], acc[mt][nt]);
        }
    }
    float bv[4];
    #pragma unroll
    for (int nt = 0; nt < 4; nt++) bv[nt] = bias[bn + wn * 64 + nt * 16 + l15];
    #pragma unroll
    for (int mt = 0; mt < 4; mt++) {
        int r0 = bm + wm * 64 + mt * 16 + lq * 4;
        #pragma unroll
        for (int nt = 0; nt < 4; nt++) {
            int col = bn + wn * 64 + nt * 16 + l15;
            #pragma unroll
            for (int rr = 0; rr < 4; rr++)
                Cout[(size_t)(r0 + rr) * Dd + col] = acc[mt][nt][rr] + bv[nt];
        }
    }
}

// ---------------- MFMA flash attention v5: exp2-fma mask fold, half-key PV pipeline ----------------
// grid (B*H, S/256), XCD-swizzled (bh fast). 512 thr = 8 waves; wave owns 32 q-rows.
// p = exp2(s*log2e + mbias); mbias=-30000 -> exactly 0 when masked.
// PV in 32-key halves reusing wave-private Ps -> PV MFMAs overlap next half's exp chain.
__global__ __launch_bounds__(512, 4) void attn_mfma(
    u16* qctx, const u16* __restrict__ Kb, const u16* __restrict__ Vt,
    const float* __restrict__ maskf, const float* __restrict__ mbias)
{
    __shared__ u16 Ks[64][72];       // [key][d]   (144B rows: 16B-aligned)
    __shared__ u16 Vs[64][72];       // [d][key]
    __shared__ u16 Ps[8][32][40];    // per-wave P half-tile [qrow][key32] (80B rows)
    const int tid = threadIdx.x, lane = tid & 63, wave = tid >> 6;
    const int l31 = lane & 31, hi = lane >> 5;
    const int bh = blockIdx.x, h = bh & 15, b = bh >> 4;
    const int q0 = blockIdx.y * 256;

    bf16x8 qa[4];
    {
        const u16* qp = qctx + (size_t)(b * Ss + q0 + wave * 32 + l31) * Dd + h * 64 + hi * 8;
        #pragma unroll
        for (int kf = 0; kf < 4; kf++) qa[kf] = ldfrag(qp + kf * 16);
    }

    const int srow = tid >> 3, scol = (tid & 7) * 8;
    const u16* kgsrc = Kb + (size_t)(b * Ss + srow) * Dd + h * 64 + scol;
    const u16* vgsrc = Vt + (size_t)((b * Hh + h) * 64 + srow) * Ss + scol;
    u16* kdst = &Ks[srow][scol];
    u16* vdst = &Vs[srow][scol];

    f32x16 acc0 = {}, acc1 = {};
    float li[16];
    #pragma unroll
    for (int r = 0; r < 16; r++) li[r] = 0.f;

    uint4 kreg = *(const uint4*)kgsrc;
    uint4 vreg = *(const uint4*)vgsrc;
    const float LOG2E = 1.44269504088896f;

    for (int k0 = 0; k0 < Ss; k0 += 64) {
        __syncthreads();
        *(uint4*)kdst = kreg;
        *(uint4*)vdst = vreg;
        __syncthreads();
        int k0n = (k0 + 64 < Ss) ? k0 + 64 : 0;
        kreg = *(const uint4*)(kgsrc + (size_t)k0n * Dd);
        vreg = *(const uint4*)(vgsrc + k0n);
        float mb[2];
        mb[0] = mbias[b * Ss + k0 + l31];
        mb[1] = mbias[b * Ss + k0 + 32 + l31];

        #pragma unroll
        for (int nt = 0; nt < 2; nt++) {
            // QK^T for this 32-key half
            f32x16 sc = {};
            #pragma unroll
            for (int kf = 0; kf < 4; kf++) {
                bf16x8 kb = ldfrag(&Ks[nt * 32 + l31][kf * 16 + hi * 8]);
                sc = mfma32(qa[kf], kb, sc);
            }
            // unshifted softmax: p = exp2(s*log2e + mbias); store round-half-up bf16
            #pragma unroll
            for (int r = 0; r < 16; r++) {
                float p = __builtin_amdgcn_exp2f(fmaf(sc[r], LOG2E, mb[nt]));
                li[r] += p;
                unsigned ub = __builtin_bit_cast(unsigned, p);
                Ps[wave][(r & 3) + 8 * (r >> 2) + 4 * hi][l31] = (u16)((ub + 0x8000u) >> 16);
            }
            // PV for this half (wave-private Ps; ds ops in program order -> safe reuse)
            #pragma unroll
            for (int kf = 0; kf < 2; kf++) {
                bf16x8 pa = ldfrag(&Ps[wave][l31][kf * 16 + hi * 8]);
                bf16x8 v0 = ldfrag(&Vs[l31][nt * 32 + kf * 16 + hi * 8]);
                bf16x8 v1 = ldfrag(&Vs[32 + l31][nt * 32 + kf * 16 + hi * 8]);
                acc0 = mfma32(pa, v0, acc0);
                acc1 = mfma32(pa, v1, acc1);
            }
        }
    }

    #pragma unroll
    for (int r = 0; r < 16; r++) {
        float s = li[r];
        s += __shfl_xor(s, 1); s += __shfl_xor(s, 2);
        s += __shfl_xor(s, 4); s += __shfl_xor(s, 8);
        s += __shfl_xor(s, 16);
        li[r] = s;
    }
    #pragma unroll
    for (int r = 0; r < 16; r++) {
        int row = (r & 3) + 8 * (r >> 2) + 4 * hi;
        int q = q0 + wave * 32 + row;
        float qm = maskf[b * Ss + q];
        float rl = li[r] > 0.f ? qm / li[r] : 0.f;
        u16* op = qctx + (size_t)(b * Ss + q) * Dd + h * 64 + l31;
        op[0]  = f2bf(acc0[r] * rl);
        op[32] = f2bf(acc1[r] * rl);
    }
}

extern "C" void kernel_launch(void* const* d_in, const int* in_sizes, int n_in,
                              void* d_out, int out_size, void* d_ws, size_t ws_size,
                              hipStream_t stream) {
    const float* X  = (const float*)d_in[0];
    const unsigned char* mr = (const unsigned char*)d_in[1];
    const float* Wq = (const float*)d_in[2];
    const float* bq = (const float*)d_in[3];
    const float* Wk = (const float*)d_in[4];
    const float* bk = (const float*)d_in[5];
    const float* Wv = (const float*)d_in[6];
    const float* bv = (const float*)d_in[7];
    const float* Wo = (const float*)d_in[8];
    const float* bo = (const float*)d_in[9];
    float* out = (float*)d_out;

    // ws (64 MB)
    u16* wsb = (u16*)d_ws;
    u16* Xh  = wsb;                // dies after QKV-gemm; Wo^T overlays
    u16* Qb  = wsb + (size_t)SZt;  // ctx aliases after attention
    u16* Kb  = wsb + 2 * (size_t)SZt;
    u16* Vt  = wsb + 3 * (size_t)SZt;
    u16* Wot = Xh;
    // d_out scratch (first ~22.1 MB; all dead before gemm_out writes d_out)
    u16* ob  = (u16*)d_out;
    u16* Xl  = ob;
    u16* Wcat = ob + (size_t)SZt;              // Wqt|Wkt|Wvt contiguous = [3072][1024]
    u16* Wqt = Wcat;
    u16* Wkt = Wqt + 1048576;
    u16* Wvt = Wkt + 1048576;
    float* mnorm = (float*)(Wvt + 1048576);    // 32 KB
    float* bcat  = mnorm + Bb * Ss;            // 12 KB
    float* mbias = bcat + 3072;                // 32 KB

    dim3 tg(32, 32), tb(32, 8);

    normalize_mask<<<1, 1024, 0, stream>>>(mr, mnorm, mbias, Bb * Ss);
    concat_bias<<<12, 256, 0, stream>>>(bq, bk, bv, bcat);
    convert_x<<<SZt / 1024, 256, 0, stream>>>(X, Xh, Xl);
    transpose_w<<<tg, tb, 0, stream>>>(Wq, Wqt);
    transpose_w<<<tg, tb, 0, stream>>>(Wk, Wkt);
    transpose_w<<<tg, tb, 0, stream>>>(Wv, Wvt);
    gemm_qkv<<<dim3(24, 64), 256, 0, stream>>>(Xh, Xl, Wcat, bcat, Qb, Kb, Vt);
    transpose_w<<<tg, tb, 0, stream>>>(Wo, Wot);               // Xh dead -> reuse
    attn_mfma<<<dim3(Bb * Hh, Ss / 256), 512, 0, stream>>>(Qb, Kb, Vt, mnorm, mbias);
    gemm_out<<<dim3(8, 64), 256, 0, stream>>>(Qb, Wot, bo, out);
}